// Round 5
// baseline (446.670 us; speedup 1.0000x reference)
//
#include <hip/hip_runtime.h>

#define NB 4
#define NN 4096
#define NE 65536
#define DIN 128
#define DB 64
#define DOUT 128
#define NT 4
#define DCAT 320

#define MT 64               // edges per tile
#define LDH (DOUT + 8)      // 136 elems, 272 B row stride (16-div)

typedef __bf16 bf16;
typedef __bf16 bf16x4 __attribute__((ext_vector_type(4)));
typedef __bf16 bf16x8 __attribute__((ext_vector_type(8)));
typedef float floatx4 __attribute__((ext_vector_type(4)));

// ---------------- prep: sites fp32->bf16, and weight repack W[t][k][n] -> Wt[t][n'][k]
#define NS4 (NB * NN * DIN / 4)      // 524288 float4 groups
#define NA  (NT * 256 * DCAT)        // 327680 WtA elems
#define NB2 (NT * 256 * DOUT)        // 131072 WtB elems
__global__ void prep_k(const float* __restrict__ sites,
                       const float* __restrict__ W1a, const float* __restrict__ W2a,
                       const float* __restrict__ W1b, const float* __restrict__ W2b,
                       bf16* __restrict__ sitesB,
                       bf16* __restrict__ WtA, bf16* __restrict__ WtB) {
    int i = blockIdx.x * 256 + threadIdx.x;
    if (i < NS4) {
        float4 f = ((const float4*)sites)[i];
        bf16x4 h = { (bf16)f.x, (bf16)f.y, (bf16)f.z, (bf16)f.w };
        ((bf16x4*)sitesB)[i] = h;
    } else if (i < NS4 + NA) {
        int j = i - NS4;
        int k = j % DCAT;
        int n = (j / DCAT) % 256;
        int t = j / (DCAT * 256);
        float w = (n < DOUT) ? W1a[(t * DCAT + k) * DOUT + n]
                             : W2a[(t * DCAT + k) * DOUT + (n - DOUT)];
        WtA[j] = (bf16)w;
    } else {
        int j = i - NS4 - NA;
        int k = j % DOUT;
        int n = (j / DOUT) % 256;
        int t = j / (DOUT * 256);
        float w = (n < DOUT) ? W1b[(t * DOUT + k) * DOUT + n]
                             : W2b[(t * DOUT + k) * DOUT + (n - DOUT)];
        WtB[j] = (bf16)w;
    }
}

// ---------------- bucket edges by type (LDS histogram) + degree count for idx2 CSR
__global__ void bucket_k(const int* __restrict__ uc, const int* __restrict__ idx2,
                         int* __restrict__ cnt, int* __restrict__ deg,
                         int* __restrict__ bucket) {
    __shared__ int h[NT];
    __shared__ int baseo[NT];
    int tid = threadIdx.x;
    if (tid < NT) h[tid] = 0;
    __syncthreads();
    int e = blockIdx.x * 256 + tid;
    int t = uc[e] & 3;
    int lp = atomicAdd(&h[t], 1);         // LDS atomic
    __syncthreads();
    if (tid < NT) baseo[tid] = atomicAdd(&cnt[tid], h[tid]);
    __syncthreads();
    bucket[t * NE + baseo[t] + lp] = e;
    atomicAdd(&deg[idx2[e] & (NN - 1)], 1);
}

// ---------------- exclusive prefix sum over deg[4096] -> off[4097] (single block)
__global__ void scan_k(const int* __restrict__ deg, int* __restrict__ off) {
    __shared__ int part[1024];
    int tid = threadIdx.x;                // 1024 threads
    int v[4]; int s = 0;
    #pragma unroll
    for (int j = 0; j < 4; ++j) { v[j] = deg[tid * 4 + j]; s += v[j]; }
    part[tid] = s;
    __syncthreads();
    for (int d = 1; d < 1024; d <<= 1) {
        int x = (tid >= d) ? part[tid - d] : 0;
        __syncthreads();
        part[tid] += x;
        __syncthreads();
    }
    int excl = (tid == 0) ? 0 : part[tid - 1];
    #pragma unroll
    for (int j = 0; j < 4; ++j) { off[tid * 4 + j] = excl; excl += v[j]; }
    if (tid == 1023) off[4096] = excl;
}

// ---------------- fill CSR edge lists
__global__ void fill_k(const int* __restrict__ idx2, const int* __restrict__ off,
                       int* __restrict__ cursor, int* __restrict__ elist) {
    int e = blockIdx.x * 256 + threadIdx.x;
    int n = idx2[e] & (NN - 1);
    int p = atomicAdd(&cursor[n], 1);
    elist[off[n] + p] = e;
}

// ---------------- main fused kernel: register-direct A-fragments, LDS only for H
__launch_bounds__(256, 4)
__global__ void main_k(const bf16* __restrict__ sitesB, const float* __restrict__ bonds,
                       const int* __restrict__ idx1, const int* __restrict__ idx2,
                       const int* __restrict__ cnt, const int* __restrict__ bucket,
                       const bf16* __restrict__ WtA, const bf16* __restrict__ WtB,
                       const float* __restrict__ b1a, const float* __restrict__ b2a,
                       const float* __restrict__ b1b, const float* __restrict__ b2b,
                       const float* __restrict__ Wa1, const float* __restrict__ ba1,
                       const float* __restrict__ Wa2, const float* __restrict__ ba2,
                       bf16* __restrict__ eo) {
    __shared__ bf16 sH1[MT * LDH];   // 17408 B
    __shared__ bf16 sH2[MT * LDH];   // 17408 B
    __shared__ int sI1[MT], sI2[MT], sEid[MT];

    const int tid = threadIdx.x;
    const int b = blockIdx.y;

    // --- map flat tile index -> (type, tile-within-type)
    int c0 = cnt[0], c1 = cnt[1], c2 = cnt[2], c3 = cnt[3];
    int n0 = (c0 + MT - 1) / MT, n1 = (c1 + MT - 1) / MT,
        n2 = (c2 + MT - 1) / MT, n3 = (c3 + MT - 1) / MT;
    int flat = blockIdx.x;
    int t, ti, cT;
    if (flat < n0)                { t = 0; ti = flat;                cT = c0; }
    else if (flat < n0+n1)        { t = 1; ti = flat - n0;           cT = c1; }
    else if (flat < n0+n1+n2)     { t = 2; ti = flat - n0 - n1;      cT = c2; }
    else if (flat < n0+n1+n2+n3)  { t = 3; ti = flat - n0 - n1 - n2; cT = c3; }
    else return;                  // uniform early-exit before any barrier
    const int base = ti * MT;
    const int nvalid = min(MT, cT - base);

    // --- phase 0: edge ids + endpoints (index-clamped)
    if (tid < MT) {
        int rr = min(tid, max(nvalid - 1, 0));
        int e = bucket[t * NE + base + rr] & (NE - 1);
        sEid[tid] = e;
        sI1[tid] = idx1[e] & (NN - 1);
        sI2[tid] = idx2[e] & (NN - 1);
    }
    __syncthreads();

    // --- wave mapping: wave w covers branch (w>>1), column half (w&1)*64
    const int wv = tid >> 6;
    const int lane = tid & 63;
    const int br = wv >> 1;
    const int nh = wv & 1;
    const int lr = lane & 15;
    const int lk = (lane >> 4) * 8;
    const int colbase = nh * 64;

    // --- per-lane A-row bases (row r = mt*16 + lr)
    const bf16* a1[4]; const bf16* a2[4]; const float* ab[4];
    #pragma unroll
    for (int mt = 0; mt < 4; ++mt) {
        int r = mt * 16 + lr;
        a1[mt] = sitesB + ((size_t)b * NN + sI1[r]) * DIN;
        a2[mt] = sitesB + ((size_t)b * NN + sI2[r]) * DIN;
        ab[mt] = bonds + ((size_t)b * NE + sEid[r]) * DB;
    }

    // --- layer 1 GEMM: [64 x 320] @ [320 x 64cols], A direct from global
    floatx4 acc[4][4];
    #pragma unroll
    for (int mt = 0; mt < 4; ++mt)
        #pragma unroll
        for (int nt = 0; nt < 4; ++nt)
            acc[mt][nt] = (floatx4){0.f, 0.f, 0.f, 0.f};

    const bf16* WtA_w = WtA + (t * 256 + br * 128 + colbase) * DCAT;
    #pragma unroll
    for (int ks = 0; ks < 10; ++ks) {
        int k = ks * 32 + lk;
        bf16x8 aF[4];
        #pragma unroll
        for (int mt = 0; mt < 4; ++mt) {
            if (ks < 4) {
                aF[mt] = *(const bf16x8*)(a1[mt] + k);
            } else if (ks < 8) {
                aF[mt] = *(const bf16x8*)(a2[mt] + (k - 128));
            } else {
                const float* p = ab[mt] + (k - 256);
                float4 f0 = *(const float4*)p;
                float4 f1 = *(const float4*)(p + 4);
                aF[mt] = (bf16x8){ (bf16)f0.x, (bf16)f0.y, (bf16)f0.z, (bf16)f0.w,
                                   (bf16)f1.x, (bf16)f1.y, (bf16)f1.z, (bf16)f1.w };
            }
        }
        #pragma unroll
        for (int nt = 0; nt < 4; ++nt) {
            bf16x8 bF = *(const bf16x8*)(&WtA_w[(nt * 16 + lr) * DCAT + k]);
            #pragma unroll
            for (int mt = 0; mt < 4; ++mt)
                acc[mt][nt] = __builtin_amdgcn_mfma_f32_16x16x32_bf16(aF[mt], bF, acc[mt][nt], 0, 0, 0);
        }
    }

    // --- bias + lrelu -> bf16 H tile in LDS
    bf16* sH = (br == 0) ? sH1 : sH2;
    const float* biasA = ((br == 0) ? b1a : b2a) + t * DOUT;
    #pragma unroll
    for (int nt = 0; nt < 4; ++nt) {
        int c = colbase + nt * 16 + lr;
        float bias = biasA[c];
        #pragma unroll
        for (int mt = 0; mt < 4; ++mt) {
            int rbase = mt * 16 + (lane >> 4) * 4;
            #pragma unroll
            for (int rg = 0; rg < 4; ++rg) {
                float v = acc[mt][nt][rg] + bias;
                v = v > 0.f ? v : 0.01f * v;
                sH[(rbase + rg) * LDH + c] = (bf16)v;
            }
        }
    }
    __syncthreads();

    // --- layer 2 GEMM: [64 x 128] @ [128 x 64cols], A = own-branch H from LDS
    floatx4 acc2[4][4];
    #pragma unroll
    for (int mt = 0; mt < 4; ++mt)
        #pragma unroll
        for (int nt = 0; nt < 4; ++nt)
            acc2[mt][nt] = (floatx4){0.f, 0.f, 0.f, 0.f};

    const bf16* sHa = (br == 0) ? sH1 : sH2;
    const bf16* WtB_w = WtB + (t * 256 + br * 128 + colbase) * DOUT;
    #pragma unroll
    for (int ks = 0; ks < 4; ++ks) {
        int k = ks * 32 + lk;
        bf16x8 aF[4];
        #pragma unroll
        for (int mt = 0; mt < 4; ++mt)
            aF[mt] = *(const bf16x8*)(&sHa[(mt * 16 + lr) * LDH + k]);
        #pragma unroll
        for (int nt = 0; nt < 4; ++nt) {
            bf16x8 bF = *(const bf16x8*)(&WtB_w[(nt * 16 + lr) * DOUT + k]);
            #pragma unroll
            for (int mt = 0; mt < 4; ++mt)
                acc2[mt][nt] = __builtin_amdgcn_mfma_f32_16x16x32_bf16(aF[mt], bF, acc2[mt][nt], 0, 0, 0);
        }
    }
    __syncthreads();   // everyone done READING sH before overwrite

    // --- bias + lrelu -> final per-branch outputs back into sH
    const float* biasB = ((br == 0) ? b1b : b2b) + t * DOUT;
    #pragma unroll
    for (int nt = 0; nt < 4; ++nt) {
        int c = colbase + nt * 16 + lr;
        float bias = biasB[c];
        #pragma unroll
        for (int mt = 0; mt < 4; ++mt) {
            int rbase = mt * 16 + (lane >> 4) * 4;
            #pragma unroll
            for (int rg = 0; rg < 4; ++rg) {
                float v = acc2[mt][nt][rg] + bias;
                v = v > 0.f ? v : 0.01f * v;
                sH[(rbase + rg) * LDH + c] = (bf16)v;
            }
        }
    }
    __syncthreads();

    // --- gate + store g1+g2 per edge (no atomics)
    {
        int m = tid >> 2;
        int q = tid & 3;
        float d1 = 0.f, d2 = 0.f;
        #pragma unroll
        for (int c = 0; c < 32; ++c) {
            int cc = q * 32 + c;
            d1 += (float)sH1[m * LDH + cc] * Wa1[cc];
            d2 += (float)sH2[m * LDH + cc] * Wa2[cc];
        }
        d1 += __shfl_xor(d1, 1); d1 += __shfl_xor(d1, 2);
        d2 += __shfl_xor(d2, 1); d2 += __shfl_xor(d2, 2);
        d1 = fminf(fmaxf(d1 + ba1[0], -30.f), 30.f);
        d2 = fminf(fmaxf(d2 + ba2[0], -30.f), 30.f);
        float s1 = 1.f / (1.f + __expf(-d1));
        float s2 = 1.f / (1.f + __expf(-d2));
        if (m < nvalid) {
            bf16* dst = eo + ((size_t)b * NE + sEid[m]) * DOUT;
            #pragma unroll
            for (int j = 0; j < 4; ++j) {
                int cc = (q + 4 * j) * 8;     // 4 consecutive lanes cover one 64B line
                bf16x8 w;
                #pragma unroll
                for (int c = 0; c < 8; ++c) {
                    int col = cc + c;
                    float v = s1 * (float)sH1[m * LDH + col] + s2 * (float)sH2[m * LDH + col];
                    w[c] = (bf16)v;
                }
                *(bf16x8*)(dst + cc) = w;
            }
        }
    }
}

// ---------------- CSR gather: out[b][n][c] = sum over edges e with idx2[e]==n of eo[b][e][c]
__global__ void gather_k(const bf16* __restrict__ eo, const int* __restrict__ off,
                         const int* __restrict__ elist, float* __restrict__ out) {
    int tid = threadIdx.x;
    int s = tid >> 7;            // node slot within block (2 nodes/block)
    int c = tid & 127;           // column
    int n = blockIdx.x * 2 + s;  // wave-uniform node -> scalar elist loads
    int b = blockIdx.y;
    int o0 = off[n], o1 = off[n + 1];
    float acc = 0.f;
    for (int i = o0; i < o1; ++i) {
        int e = elist[i];
        acc += (float)eo[((size_t)b * NE + e) * DOUT + c];
    }
    out[((size_t)b * NN + n) * DOUT + c] = acc;
}

extern "C" void kernel_launch(void* const* d_in, const int* in_sizes, int n_in,
                              void* d_out, int out_size, void* d_ws, size_t ws_size,
                              hipStream_t stream) {
    const float* sites = (const float*)d_in[0];
    const float* bonds = (const float*)d_in[1];
    const int*   idx1  = (const int*)d_in[2];
    const int*   idx2  = (const int*)d_in[3];
    const int*   uc    = (const int*)d_in[4];
    const float* W1a = (const float*)d_in[5];
    const float* b1a = (const float*)d_in[6];
    const float* W1b = (const float*)d_in[7];
    const float* b1b = (const float*)d_in[8];
    const float* W2a = (const float*)d_in[9];
    const float* b2a = (const float*)d_in[10];
    const float* W2b = (const float*)d_in[11];
    const float* b2b = (const float*)d_in[12];
    const float* Wa1 = (const float*)d_in[13];
    const float* ba1 = (const float*)d_in[14];
    const float* Wa2 = (const float*)d_in[15];
    const float* ba2 = (const float*)d_in[16];
    float* out = (float*)d_out;

    char* ws = (char*)d_ws;
    // layout: [cnt][deg][cursor] | [off][bucket][elist][WtA][WtB][sitesB][eo]
    size_t o_cnt    = 0;
    size_t o_deg    = 64;
    size_t o_cursor = o_deg + NN * 4;
    size_t o_off    = o_cursor + NN * 4;            // 32832; zeroed region = [0, o_off)
    size_t o_bucket = o_off + (NN + 16) * 4;
    size_t o_elist  = o_bucket + (size_t)NT * NE * 4;
    size_t o_wta    = o_elist + (size_t)NE * 4;
    size_t o_wtb    = o_wta + (size_t)NA * 2;
    size_t o_sitesB = o_wtb + (size_t)NB2 * 2;
    size_t o_eo     = o_sitesB + (size_t)NB * NN * DIN * 2;
    size_t need     = o_eo + (size_t)NB * NE * DOUT * 2;   // ~70.2 MiB
    if (ws_size < need) return;   // diagnostic: out stays poisoned

    int*  cnt    = (int*)(ws + o_cnt);
    int*  deg    = (int*)(ws + o_deg);
    int*  cursor = (int*)(ws + o_cursor);
    int*  off    = (int*)(ws + o_off);
    int*  bucket = (int*)(ws + o_bucket);
    int*  elist  = (int*)(ws + o_elist);
    bf16* WtA    = (bf16*)(ws + o_wta);
    bf16* WtB    = (bf16*)(ws + o_wtb);
    bf16* sitesB = (bf16*)(ws + o_sitesB);
    bf16* eo     = (bf16*)(ws + o_eo);

    hipMemsetAsync(ws, 0, o_off, stream);   // cnt + deg + cursor

    prep_k<<<(NS4 + NA + NB2) / 256, 256, 0, stream>>>(sites, W1a, W2a, W1b, W2b,
                                                       sitesB, WtA, WtB);
    bucket_k<<<NE / 256, 256, 0, stream>>>(uc, idx2, cnt, deg, bucket);
    scan_k<<<1, 1024, 0, stream>>>(deg, off);
    fill_k<<<NE / 256, 256, 0, stream>>>(idx2, off, cursor, elist);

    const int maxTiles = NE / MT + NT;   // 1028 worst-case tiles over all types
    main_k<<<dim3(maxTiles, NB), 256, 0, stream>>>(
        sitesB, bonds, idx1, idx2, cnt, bucket, WtA, WtB,
        b1a, b2a, b1b, b2b, Wa1, ba1, Wa2, ba2, eo);

    gather_k<<<dim3(NN / 2, NB), 256, 0, stream>>>(eo, off, elist, out);
}

// Round 6
// 414.392 us; speedup vs baseline: 1.0779x; 1.0779x over previous
//
#include <hip/hip_runtime.h>

#define NB 4
#define NN 4096
#define NE 65536
#define DIN 128
#define DB 64
#define DOUT 128
#define NT 4
#define DCAT 320

#define MT 64               // edges per tile
#define LDH (DOUT + 8)      // 136 elems, 272 B row stride (16-div)

typedef __bf16 bf16;
typedef __bf16 bf16x4 __attribute__((ext_vector_type(4)));
typedef __bf16 bf16x8 __attribute__((ext_vector_type(8)));
typedef float floatx4 __attribute__((ext_vector_type(4)));

// ---------------- prep: zero counters, sites fp32->bf16, weight repack W[t][k][n] -> Wt[t][n'][k]
#define NS4 (NB * NN * DIN / 4)      // 524288 float4 groups
#define NA  (NT * 256 * DCAT)        // 327680 WtA elems
#define NB2 (NT * 256 * DOUT)        // 131072 WtB elems
#define NZERO 8208                   // cnt(4+12pad) + deg(4096) + cursor(4096) ints
__global__ void prep_k(const float* __restrict__ sites,
                       const float* __restrict__ W1a, const float* __restrict__ W2a,
                       const float* __restrict__ W1b, const float* __restrict__ W2b,
                       bf16* __restrict__ sitesB,
                       bf16* __restrict__ WtA, bf16* __restrict__ WtB,
                       int* __restrict__ zeroRegion) {
    int i = blockIdx.x * 256 + threadIdx.x;
    if (i < NZERO) zeroRegion[i] = 0;
    if (i < NS4) {
        float4 f = ((const float4*)sites)[i];
        bf16x4 h = { (bf16)f.x, (bf16)f.y, (bf16)f.z, (bf16)f.w };
        ((bf16x4*)sitesB)[i] = h;
    } else if (i < NS4 + NA) {
        int j = i - NS4;
        int k = j % DCAT;
        int n = (j / DCAT) % 256;
        int t = j / (DCAT * 256);
        float w = (n < DOUT) ? W1a[(t * DCAT + k) * DOUT + n]
                             : W2a[(t * DCAT + k) * DOUT + (n - DOUT)];
        WtA[j] = (bf16)w;
    } else {
        int j = i - NS4 - NA;
        int k = j % DOUT;
        int n = (j / DOUT) % 256;
        int t = j / (DOUT * 256);
        float w = (n < DOUT) ? W1b[(t * DOUT + k) * DOUT + n]
                             : W2b[(t * DOUT + k) * DOUT + (n - DOUT)];
        WtB[j] = (bf16)w;
    }
}

// ---------------- bucket edges by type (LDS histogram) + degree count for idx2 CSR
__global__ void bucket_k(const int* __restrict__ uc, const int* __restrict__ idx2,
                         int* __restrict__ cnt, int* __restrict__ deg,
                         int* __restrict__ bucket) {
    __shared__ int h[NT];
    __shared__ int baseo[NT];
    int tid = threadIdx.x;
    if (tid < NT) h[tid] = 0;
    __syncthreads();
    int e = blockIdx.x * 256 + tid;
    int t = uc[e] & 3;
    int lp = atomicAdd(&h[t], 1);         // LDS atomic
    __syncthreads();
    if (tid < NT) baseo[tid] = atomicAdd(&cnt[tid], h[tid]);
    __syncthreads();
    bucket[t * NE + baseo[t] + lp] = e;
    atomicAdd(&deg[idx2[e] & (NN - 1)], 1);
}

// ---------------- exclusive prefix sum deg[4096] -> off[4097]; 256 thr, shuffle scan
__global__ void scan_k(const int* __restrict__ deg, int* __restrict__ off) {
    __shared__ int wsum[4];
    int tid = threadIdx.x;                // 256 threads, each owns 16 elems
    int lane = tid & 63, w = tid >> 6;
    int v[16]; int s = 0;
    #pragma unroll
    for (int j = 0; j < 16; ++j) { v[j] = deg[tid * 16 + j]; s += v[j]; }
    // intra-wave inclusive scan of s
    int inc = s;
    #pragma unroll
    for (int d = 1; d < 64; d <<= 1) {
        int x = __shfl_up(inc, d, 64);
        if (lane >= d) inc += x;
    }
    if (lane == 63) wsum[w] = inc;
    __syncthreads();
    int wpre = 0;
    #pragma unroll
    for (int j = 0; j < 4; ++j) wpre += (j < w) ? wsum[j] : 0;
    int excl = wpre + inc - s;            // exclusive prefix for this thread's chunk
    #pragma unroll
    for (int j = 0; j < 16; ++j) { off[tid * 16 + j] = excl; excl += v[j]; }
    if (tid == 255) off[4096] = excl;
}

// ---------------- fill CSR edge lists
__global__ void fill_k(const int* __restrict__ idx2, const int* __restrict__ off,
                       int* __restrict__ cursor, int* __restrict__ elist) {
    int e = blockIdx.x * 256 + threadIdx.x;
    int n = idx2[e] & (NN - 1);
    int p = atomicAdd(&cursor[n], 1);
    elist[off[n] + p] = e;
}

// ---------------- main fused kernel: register-direct A-fragments, XCD-pinned batches
__launch_bounds__(256, 4)
__global__ void main_k(const bf16* __restrict__ sitesB, const float* __restrict__ bonds,
                       const int* __restrict__ idx1, const int* __restrict__ idx2,
                       const int* __restrict__ cnt, const int* __restrict__ bucket,
                       const bf16* __restrict__ WtA, const bf16* __restrict__ WtB,
                       const float* __restrict__ b1a, const float* __restrict__ b2a,
                       const float* __restrict__ b1b, const float* __restrict__ b2b,
                       const float* __restrict__ Wa1, const float* __restrict__ ba1,
                       const float* __restrict__ Wa2, const float* __restrict__ ba2,
                       bf16* __restrict__ eo) {
    __shared__ bf16 sH1[MT * LDH];   // 17408 B
    __shared__ bf16 sH2[MT * LDH];   // 17408 B
    __shared__ int sI1[MT], sI2[MT], sEid[MT];

    const int tid = threadIdx.x;

    // --- XCD-pinned decode: consecutive blocks round-robin XCDs (blk%8 = XCD).
    //     b = (blk%8)>>1 pins each batch to 2 XCDs -> sitesB[b] (1MB) + weights
    //     (1.75MB) stay resident in that XCD's 4MB L2.
    int blk = blockIdx.x;
    int p = blk & 7;
    const int b = p >> 1;
    int flat = ((blk >> 3) << 1) + (p & 1);   // tile index within batch, 0..1027

    // --- map flat tile index -> (type, tile-within-type)
    int c0 = cnt[0], c1 = cnt[1], c2 = cnt[2], c3 = cnt[3];
    int n0 = (c0 + MT - 1) / MT, n1 = (c1 + MT - 1) / MT,
        n2 = (c2 + MT - 1) / MT, n3 = (c3 + MT - 1) / MT;
    int t, ti, cT;
    if (flat < n0)                { t = 0; ti = flat;                cT = c0; }
    else if (flat < n0+n1)        { t = 1; ti = flat - n0;           cT = c1; }
    else if (flat < n0+n1+n2)     { t = 2; ti = flat - n0 - n1;      cT = c2; }
    else if (flat < n0+n1+n2+n3)  { t = 3; ti = flat - n0 - n1 - n2; cT = c3; }
    else return;                  // uniform early-exit before any barrier
    const int base = ti * MT;
    const int nvalid = min(MT, cT - base);

    // --- phase 0: edge ids + endpoints (index-clamped)
    if (tid < MT) {
        int rr = min(tid, max(nvalid - 1, 0));
        int e = bucket[t * NE + base + rr] & (NE - 1);
        sEid[tid] = e;
        sI1[tid] = idx1[e] & (NN - 1);
        sI2[tid] = idx2[e] & (NN - 1);
    }
    __syncthreads();

    // --- wave mapping: wave w covers branch (w>>1), column half (w&1)*64
    const int wv = tid >> 6;
    const int lane = tid & 63;
    const int br = wv >> 1;
    const int nh = wv & 1;
    const int lr = lane & 15;
    const int lk = (lane >> 4) * 8;
    const int colbase = nh * 64;

    // --- per-lane A-row bases (row r = mt*16 + lr)
    const bf16* a1[4]; const bf16* a2[4]; const float* ab[4];
    #pragma unroll
    for (int mt = 0; mt < 4; ++mt) {
        int r = mt * 16 + lr;
        a1[mt] = sitesB + ((size_t)b * NN + sI1[r]) * DIN;
        a2[mt] = sitesB + ((size_t)b * NN + sI2[r]) * DIN;
        ab[mt] = bonds + ((size_t)b * NE + sEid[r]) * DB;
    }

    // --- layer 1 GEMM: [64 x 320] @ [320 x 64cols], A direct from global
    floatx4 acc[4][4];
    #pragma unroll
    for (int mt = 0; mt < 4; ++mt)
        #pragma unroll
        for (int nt = 0; nt < 4; ++nt)
            acc[mt][nt] = (floatx4){0.f, 0.f, 0.f, 0.f};

    const bf16* WtA_w = WtA + (t * 256 + br * 128 + colbase) * DCAT;
    #pragma unroll
    for (int ks = 0; ks < 10; ++ks) {
        int k = ks * 32 + lk;
        bf16x8 aF[4];
        #pragma unroll
        for (int mt = 0; mt < 4; ++mt) {
            if (ks < 4) {
                aF[mt] = *(const bf16x8*)(a1[mt] + k);
            } else if (ks < 8) {
                aF[mt] = *(const bf16x8*)(a2[mt] + (k - 128));
            } else {
                const float* p2 = ab[mt] + (k - 256);
                float4 f0 = *(const float4*)p2;
                float4 f1 = *(const float4*)(p2 + 4);
                aF[mt] = (bf16x8){ (bf16)f0.x, (bf16)f0.y, (bf16)f0.z, (bf16)f0.w,
                                   (bf16)f1.x, (bf16)f1.y, (bf16)f1.z, (bf16)f1.w };
            }
        }
        #pragma unroll
        for (int nt = 0; nt < 4; ++nt) {
            bf16x8 bF = *(const bf16x8*)(&WtA_w[(nt * 16 + lr) * DCAT + k]);
            #pragma unroll
            for (int mt = 0; mt < 4; ++mt)
                acc[mt][nt] = __builtin_amdgcn_mfma_f32_16x16x32_bf16(aF[mt], bF, acc[mt][nt], 0, 0, 0);
        }
    }

    // --- bias + lrelu -> bf16 H tile in LDS
    bf16* sH = (br == 0) ? sH1 : sH2;
    const float* biasA = ((br == 0) ? b1a : b2a) + t * DOUT;
    #pragma unroll
    for (int nt = 0; nt < 4; ++nt) {
        int c = colbase + nt * 16 + lr;
        float bias = biasA[c];
        #pragma unroll
        for (int mt = 0; mt < 4; ++mt) {
            int rbase = mt * 16 + (lane >> 4) * 4;
            #pragma unroll
            for (int rg = 0; rg < 4; ++rg) {
                float v = acc[mt][nt][rg] + bias;
                v = v > 0.f ? v : 0.01f * v;
                sH[(rbase + rg) * LDH + c] = (bf16)v;
            }
        }
    }
    __syncthreads();

    // --- layer 2 GEMM: [64 x 128] @ [128 x 64cols], A = own-branch H from LDS
    floatx4 acc2[4][4];
    #pragma unroll
    for (int mt = 0; mt < 4; ++mt)
        #pragma unroll
        for (int nt = 0; nt < 4; ++nt)
            acc2[mt][nt] = (floatx4){0.f, 0.f, 0.f, 0.f};

    const bf16* sHa = (br == 0) ? sH1 : sH2;
    const bf16* WtB_w = WtB + (t * 256 + br * 128 + colbase) * DOUT;
    #pragma unroll
    for (int ks = 0; ks < 4; ++ks) {
        int k = ks * 32 + lk;
        bf16x8 aF[4];
        #pragma unroll
        for (int mt = 0; mt < 4; ++mt)
            aF[mt] = *(const bf16x8*)(&sHa[(mt * 16 + lr) * LDH + k]);
        #pragma unroll
        for (int nt = 0; nt < 4; ++nt) {
            bf16x8 bF = *(const bf16x8*)(&WtB_w[(nt * 16 + lr) * DOUT + k]);
            #pragma unroll
            for (int mt = 0; mt < 4; ++mt)
                acc2[mt][nt] = __builtin_amdgcn_mfma_f32_16x16x32_bf16(aF[mt], bF, acc2[mt][nt], 0, 0, 0);
        }
    }
    __syncthreads();   // everyone done READING sH before overwrite

    // --- bias + lrelu -> final per-branch outputs back into sH
    const float* biasB = ((br == 0) ? b1b : b2b) + t * DOUT;
    #pragma unroll
    for (int nt = 0; nt < 4; ++nt) {
        int c = colbase + nt * 16 + lr;
        float bias = biasB[c];
        #pragma unroll
        for (int mt = 0; mt < 4; ++mt) {
            int rbase = mt * 16 + (lane >> 4) * 4;
            #pragma unroll
            for (int rg = 0; rg < 4; ++rg) {
                float v = acc2[mt][nt][rg] + bias;
                v = v > 0.f ? v : 0.01f * v;
                sH[(rbase + rg) * LDH + c] = (bf16)v;
            }
        }
    }
    __syncthreads();

    // --- gate + store g1+g2 per edge (no atomics)
    {
        int m = tid >> 2;
        int q = tid & 3;
        float d1 = 0.f, d2 = 0.f;
        #pragma unroll
        for (int c = 0; c < 32; ++c) {
            int cc = q * 32 + c;
            d1 += (float)sH1[m * LDH + cc] * Wa1[cc];
            d2 += (float)sH2[m * LDH + cc] * Wa2[cc];
        }
        d1 += __shfl_xor(d1, 1); d1 += __shfl_xor(d1, 2);
        d2 += __shfl_xor(d2, 1); d2 += __shfl_xor(d2, 2);
        d1 = fminf(fmaxf(d1 + ba1[0], -30.f), 30.f);
        d2 = fminf(fmaxf(d2 + ba2[0], -30.f), 30.f);
        float s1 = 1.f / (1.f + __expf(-d1));
        float s2 = 1.f / (1.f + __expf(-d2));
        if (m < nvalid) {
            bf16* dst = eo + ((size_t)b * NE + sEid[m]) * DOUT;
            #pragma unroll
            for (int j = 0; j < 4; ++j) {
                int cc = (q + 4 * j) * 8;     // 4 consecutive lanes cover one 64B line
                bf16x8 w;
                #pragma unroll
                for (int c = 0; c < 8; ++c) {
                    int col = cc + c;
                    float v = s1 * (float)sH1[m * LDH + col] + s2 * (float)sH2[m * LDH + col];
                    w[c] = (bf16)v;
                }
                *(bf16x8*)(dst + cc) = w;
            }
        }
    }
}

// ---------------- CSR gather, unroll-4: out[b][n][c] = sum_e eo[b][e][c]
__global__ void gather_k(const bf16* __restrict__ eo, const int* __restrict__ off,
                         const int* __restrict__ elist, float* __restrict__ out) {
    int tid = threadIdx.x;
    int s = tid >> 7;            // node slot within block (2 nodes/block)
    int c = tid & 127;           // column
    int n = blockIdx.x * 2 + s;  // wave-uniform node -> scalar elist loads
    int b = blockIdx.y;
    int o0 = off[n], o1 = off[n + 1];
    const bf16* eob = eo + (size_t)b * NE * DOUT + c;
    float a0 = 0.f, a1 = 0.f, a2 = 0.f, a3 = 0.f;
    int i = o0;
    for (; i + 3 < o1; i += 4) {
        int e0 = elist[i], e1 = elist[i + 1], e2 = elist[i + 2], e3 = elist[i + 3];
        a0 += (float)eob[(size_t)e0 * DOUT];
        a1 += (float)eob[(size_t)e1 * DOUT];
        a2 += (float)eob[(size_t)e2 * DOUT];
        a3 += (float)eob[(size_t)e3 * DOUT];
    }
    for (; i < o1; ++i)
        a0 += (float)eob[(size_t)elist[i] * DOUT];
    out[((size_t)b * NN + n) * DOUT + c] = (a0 + a1) + (a2 + a3);
}

extern "C" void kernel_launch(void* const* d_in, const int* in_sizes, int n_in,
                              void* d_out, int out_size, void* d_ws, size_t ws_size,
                              hipStream_t stream) {
    const float* sites = (const float*)d_in[0];
    const float* bonds = (const float*)d_in[1];
    const int*   idx1  = (const int*)d_in[2];
    const int*   idx2  = (const int*)d_in[3];
    const int*   uc    = (const int*)d_in[4];
    const float* W1a = (const float*)d_in[5];
    const float* b1a = (const float*)d_in[6];
    const float* W1b = (const float*)d_in[7];
    const float* b1b = (const float*)d_in[8];
    const float* W2a = (const float*)d_in[9];
    const float* b2a = (const float*)d_in[10];
    const float* W2b = (const float*)d_in[11];
    const float* b2b = (const float*)d_in[12];
    const float* Wa1 = (const float*)d_in[13];
    const float* ba1 = (const float*)d_in[14];
    const float* Wa2 = (const float*)d_in[15];
    const float* ba2 = (const float*)d_in[16];
    float* out = (float*)d_out;

    char* ws = (char*)d_ws;
    // layout: [cnt(64B)|deg|cursor] | [off][bucket][elist][WtA][WtB][sitesB][eo]
    size_t o_cnt    = 0;
    size_t o_deg    = 64;
    size_t o_cursor = o_deg + NN * 4;
    size_t o_off    = o_cursor + NN * 4;            // 32832B = NZERO*4
    size_t o_bucket = o_off + (NN + 16) * 4;
    size_t o_elist  = o_bucket + (size_t)NT * NE * 4;
    size_t o_wta    = o_elist + (size_t)NE * 4;
    size_t o_wtb    = o_wta + (size_t)NA * 2;
    size_t o_sitesB = o_wtb + (size_t)NB2 * 2;
    size_t o_eo     = o_sitesB + (size_t)NB * NN * DIN * 2;
    size_t need     = o_eo + (size_t)NB * NE * DOUT * 2;   // ~70.2 MiB
    if (ws_size < need) return;   // diagnostic: out stays poisoned

    int*  cnt    = (int*)(ws + o_cnt);
    int*  deg    = (int*)(ws + o_deg);
    int*  cursor = (int*)(ws + o_cursor);
    int*  off    = (int*)(ws + o_off);
    int*  bucket = (int*)(ws + o_bucket);
    int*  elist  = (int*)(ws + o_elist);
    bf16* WtA    = (bf16*)(ws + o_wta);
    bf16* WtB    = (bf16*)(ws + o_wtb);
    bf16* sitesB = (bf16*)(ws + o_sitesB);
    bf16* eo     = (bf16*)(ws + o_eo);

    prep_k<<<(NS4 + NA + NB2) / 256, 256, 0, stream>>>(sites, W1a, W2a, W1b, W2b,
                                                       sitesB, WtA, WtB, (int*)ws);
    bucket_k<<<NE / 256, 256, 0, stream>>>(uc, idx2, cnt, deg, bucket);
    scan_k<<<1, 256, 0, stream>>>(deg, off);
    fill_k<<<NE / 256, 256, 0, stream>>>(idx2, off, cursor, elist);

    const int maxTiles = NE / MT + NT;   // 1028 tiles/batch worst case
    main_k<<<maxTiles * NB, 256, 0, stream>>>(    // flat grid, XCD-pinned decode
        sitesB, bonds, idx1, idx2, cnt, bucket, WtA, WtB,
        b1a, b2a, b1b, b2b, Wa1, ba1, Wa2, ba2, eo);

    gather_k<<<dim3(NN / 2, NB), 256, 0, stream>>>(eo, off, elist, out);
}